// Round 6
// baseline (233.967 us; speedup 1.0000x reference)
//
#include <hip/hip_runtime.h>
#include <math.h>

#define SCALE 0.35355339059327373f
#define EPSV 1e-5f

typedef __attribute__((ext_vector_type(8))) short bf16x8;
typedef __attribute__((ext_vector_type(4))) float f32x4;
typedef __attribute__((ext_vector_type(16))) float f32x16;
typedef __attribute__((ext_vector_type(4))) int i32x4;
typedef __attribute__((ext_vector_type(2))) int i32x2;

static __device__ __forceinline__ unsigned short bfh(float f) {
    return (unsigned short)(__builtin_bit_cast(unsigned int, f) >> 16);
}
static __device__ __forceinline__ float bf2f(unsigned short s) {
    return __builtin_bit_cast(float, (unsigned int)s << 16);
}
static __device__ __forceinline__ int pack2(float lo, float hi) {
    return __builtin_amdgcn_perm(__builtin_bit_cast(unsigned int, hi),
                                 __builtin_bit_cast(unsigned int, lo), 0x07060302u);
}

// ws layout: [0,8192) ushort wqk B-frags (q-half pre-scaled by SCALE);
//            [8192,40960) ushort W2^T B-frags; byte 81920: float bnA[64], bnB[64]
__global__ void prep_kernel(const float* __restrict__ w_qk,
                            const float* __restrict__ conv_w,
                            const float* __restrict__ conv_b,
                            const float* __restrict__ bn_g, const float* __restrict__ bn_b,
                            const float* __restrict__ bn_m, const float* __restrict__ bn_v,
                            unsigned short* __restrict__ ws) {
    int i = blockIdx.x * 256 + threadIdx.x;
    if (i < 8192) {
        int f = i >> 9, rem = i & 511, l = rem >> 3, j = rem & 7;
        int nt = f >> 1, ks = f & 1;
        int k = ks * 32 + (l >> 4) * 8 + j;
        int nn = nt * 16 + (l & 15);
        float w = w_qk[k * 128 + nn];
        if (nt < 4) w *= SCALE;          // fold dot-product scale into q weights
        ws[i] = bfh(w);
    } else if (i < 40960) {
        int i2 = i - 8192;
        int g = i2 >> 9, rem = i2 & 511, l = rem >> 3, j = rem & 7;
        int h = g >> 3, nt = (g >> 1) & 3, ks = g & 1;
        int c = ks * 32 + (l >> 4) * 8 + j;
        int o = nt * 16 + (l & 15);
        ws[i] = bfh(conv_w[h * 4096 + o * 64 + c]);
    } else if (i < 41024) {
        int o = i - 40960;
        float gv = bn_g[o] * rsqrtf(bn_v[o] + EPSV);
        float bb = bn_b[o] - bn_m[o] * gv;
        float cb = 0.f;
        for (int h = 0; h < 8; h++) cb += conv_b[h * 64 + o];
        float* wsf = (float*)(ws + 40960);
        wsf[o] = gv;
        wsf[64 + o] = bb + cb * gv;
    }
}

// One WAVE per (n,t) tile; 4 waves/block; no __syncthreads, no explicit waitcnt
// (same-wave DS ops are processed in order; compiler inserts minimal lgkm waits).
// Per-wave LDS (9728 B):
//   [0   ,5120) xb16[32][72]u16  (later FWT[64][40]u16, union)
//   [5120,7168) mus/rss fp32 (transient) then qbuf[32][16]u16, kbuf@6144[32][16]u16
//   [7168,9728) Gh[32][40]u16  (single head: dots -> gated attn)
// Block LDS = 4*9728 = 38912 -> 4 blocks/CU = 16 waves/CU.
__global__ __launch_bounds__(256, 4)
void sagc_kernel(const float* __restrict__ x,
                 const float* __restrict__ ln_g, const float* __restrict__ ln_b,
                 const float* __restrict__ b_qk,
                 const float* __restrict__ topo,
                 const unsigned short* __restrict__ ws,
                 float* __restrict__ out)
{
    __shared__ __align__(16) unsigned char smem[38912];
    const int tid = threadIdx.x;
    const int lane = tid & 63, wv = tid >> 6;
    const int l15 = lane & 15, quad = lane >> 4;
    const int r32 = lane & 31, hi = lane >> 5;

    unsigned char* my = smem + wv * 9728;
    unsigned short* xb16 = (unsigned short*)my;            // [32][72]
    unsigned short* FWT  = (unsigned short*)my;            // [64][40] (after xb16 dead)
    float*          mus  = (float*)(my + 5120);            // [32] (transient)
    float*          rss  = mus + 32;                       // [32] (transient)
    unsigned short* qbuf = (unsigned short*)(my + 5120);   // [32][16]
    unsigned short* kbuf = (unsigned short*)(my + 6144);   // [32][16]
    unsigned short* Gh   = (unsigned short*)(my + 7168);   // [32][40]

    const unsigned short* wqk = ws;
    const unsigned short* w2f = ws + 8192;
    const float* bnA = (const float*)(ws + 40960);
    const float* bnB = bnA + 64;

    const int tile = blockIdx.x * 4 + wv;
    const int n = tile >> 8, t = tile & 255;
    const float* xg = x + (size_t)n * 409600 + (size_t)t * 25;   // + c*6400 + v
    float* og = out + (size_t)n * 409600 + (size_t)t * 25;

    // ---- stage x -> xb16 [v][c] bf16 (rows 25..31 zeroed: keeps FWT pad cols finite) ----
    #pragma unroll
    for (int it = 0; it < 25; it++) {
        int i = it * 64 + lane;
        int c = i / 25, v = i - c * 25;
        xb16[v * 72 + c] = bfh(xg[c * 6400 + v]);
    }
    #pragma unroll
    for (int k = 0; k < 8; k++) {
        int idx = k * 64 + lane;
        if (idx < 504) {
            int rr = idx / 72, cc = idx - rr * 72;
            xb16[(25 + rr) * 72 + cc] = 0;
        }
    }

    // ---- x A-frags + unpack + squares ----
    bf16x8 xa[2][2];
    #pragma unroll
    for (int mt = 0; mt < 2; mt++)
        #pragma unroll
        for (int ks = 0; ks < 2; ks++)
            xa[mt][ks] = *(const bf16x8*)&xb16[(mt * 16 + l15) * 72 + ks * 32 + quad * 8];

    float xf[2][2][8];
    bf16x8 sqf[2][2];
    #pragma unroll
    for (int mt = 0; mt < 2; mt++)
        #pragma unroll
        for (int ks = 0; ks < 2; ks++) {
            float s[8];
            #pragma unroll
            for (int j = 0; j < 8; j++) {
                xf[mt][ks][j] = bf2f((unsigned short)xa[mt][ks][j]);
                s[j] = xf[mt][ks][j] * xf[mt][ks][j];
            }
            i32x4 p;
            #pragma unroll
            for (int q = 0; q < 4; q++) p[q] = pack2(s[2 * q], s[2 * q + 1]);
            sqf[mt][ks] = __builtin_bit_cast(bf16x8, p);
        }

    // ---- LN stats via MFMA (B = ones * 1/64) ----
    {
        i32x4 ones_i = {0x3C803C80, 0x3C803C80, 0x3C803C80, 0x3C803C80};
        bf16x8 onesf = __builtin_bit_cast(bf16x8, ones_i);
        f32x4 z4i = {0.f, 0.f, 0.f, 0.f};
        f32x4 dmu[2], ds2[2];
        #pragma unroll
        for (int mt = 0; mt < 2; mt++) {
            dmu[mt] = __builtin_amdgcn_mfma_f32_16x16x32_bf16(xa[mt][0], onesf, z4i, 0, 0, 0);
            dmu[mt] = __builtin_amdgcn_mfma_f32_16x16x32_bf16(xa[mt][1], onesf, dmu[mt], 0, 0, 0);
            ds2[mt] = __builtin_amdgcn_mfma_f32_16x16x32_bf16(sqf[mt][0], onesf, z4i, 0, 0, 0);
            ds2[mt] = __builtin_amdgcn_mfma_f32_16x16x32_bf16(sqf[mt][1], onesf, ds2[mt], 0, 0, 0);
        }
        if (l15 == 0) {
            #pragma unroll
            for (int mt = 0; mt < 2; mt++)
                #pragma unroll
                for (int r = 0; r < 4; r++) {
                    int v = mt * 16 + quad * 4 + r;
                    float mu = dmu[mt][r];
                    float var = ds2[mt][r] - mu * mu;
                    mus[v] = mu;
                    rss[v] = rsqrtf(var + EPSV);
                }
        }
    }

    // ---- normalize in-register -> yn A-frags ----
    bf16x8 yna[2][2];
    {
        float muv[2] = {mus[l15], mus[16 + l15]};
        float rsv[2] = {rss[l15], rss[16 + l15]};
        #pragma unroll
        for (int ks = 0; ks < 2; ks++) {
            f32x4 ga = *(const f32x4*)&ln_g[ks * 32 + quad * 8];
            f32x4 gb = *(const f32x4*)&ln_g[ks * 32 + quad * 8 + 4];
            f32x4 ba = *(const f32x4*)&ln_b[ks * 32 + quad * 8];
            f32x4 bb = *(const f32x4*)&ln_b[ks * 32 + quad * 8 + 4];
            #pragma unroll
            for (int mt = 0; mt < 2; mt++) {
                float yv[8];
                #pragma unroll
                for (int j = 0; j < 8; j++) {
                    float g = (j < 4) ? ga[j] : gb[j - 4];
                    float bt = (j < 4) ? ba[j] : bb[j - 4];
                    yv[j] = (xf[mt][ks][j] - muv[mt]) * rsv[mt] * g + bt;
                }
                i32x4 p;
                #pragma unroll
                for (int q = 0; q < 4; q++) p[q] = pack2(yv[2 * q], yv[2 * q + 1]);
                yna[mt][ks] = __builtin_bit_cast(bf16x8, p);
            }
        }
    }

    // ---- accumulators for out = sum_h G_h @ FW_h ----
    f32x4 acc[2][4];
    #pragma unroll
    for (int mt = 0; mt < 2; mt++)
        #pragma unroll
        for (int nt = 0; nt < 4; nt++)
            acc[mt][nt] = (f32x4){0.f, 0.f, 0.f, 0.f};

    const f32x4 z4 = {0.f, 0.f, 0.f, 0.f};
    const bf16x8 z8 = {0, 0, 0, 0, 0, 0, 0, 0};

    // ---- per-head loop ----
    for (int h = 0; h < 8; h++) {
        const int hp = h >> 1, hl = h & 1;
        if (hl == 0) {
            // compute q,k for this head pair -> qbuf/kbuf (SCALE pre-folded for q)
            #pragma unroll
            for (int tsel = 0; tsel < 2; tsel++) {
                int nt = tsel ? (4 + hp) : hp;
                bf16x8 b0 = *(const bf16x8*)&wqk[(nt * 2 + 0) * 512 + lane * 8];
                bf16x8 b1 = *(const bf16x8*)&wqk[(nt * 2 + 1) * 512 + lane * 8];
                float bias = b_qk[(tsel ? 64 : 0) + hp * 16 + l15];
                if (!tsel) bias *= SCALE;
                unsigned short* buf = tsel ? kbuf : qbuf;
                #pragma unroll
                for (int mt = 0; mt < 2; mt++) {
                    f32x4 d = __builtin_amdgcn_mfma_f32_16x16x32_bf16(yna[mt][0], b0, z4, 0, 0, 0);
                    d = __builtin_amdgcn_mfma_f32_16x16x32_bf16(yna[mt][1], b1, d, 0, 0, 0);
                    #pragma unroll
                    for (int r = 0; r < 4; r++) {
                        int u = mt * 16 + quad * 4 + r;
                        if (u < 25) buf[u * 16 + l15] = bfh(d[r] + bias);
                    }
                }
            }
        }

        // dots: one 32x32x16 MFMA (K=8 real + 8 zero via upper half-wave)
        {
            bf16x8 aq = z8, bk = z8;
            if (hi == 0) {
                aq = *(const bf16x8*)&qbuf[r32 * 16 + hl * 8];
                bk = *(const bf16x8*)&kbuf[r32 * 16 + hl * 8];
            }
            f32x16 dd = {0.f,0.f,0.f,0.f,0.f,0.f,0.f,0.f,0.f,0.f,0.f,0.f,0.f,0.f,0.f,0.f};
            dd = __builtin_amdgcn_mfma_f32_32x32x16_bf16(aq, bk, dd, 0, 0, 0);
            #pragma unroll
            for (int r = 0; r < 16; r++) {
                int u = (r & 3) + 8 * (r >> 2) + 4 * hi;
                if (u < 25) Gh[u * 40 + r32] = bfh(dd[r]);
            }
        }

        // FW_h = feat @ W2^T_h (independent of dots/softmax; overlaps their latency)
        #pragma unroll
        for (int nt = 0; nt < 4; nt++) {
            bf16x8 w0 = *(const bf16x8*)&w2f[((h * 4 + nt) * 2 + 0) * 512 + lane * 8];
            bf16x8 w1 = *(const bf16x8*)&w2f[((h * 4 + nt) * 2 + 1) * 512 + lane * 8];
            f32x4 dw0 = __builtin_amdgcn_mfma_f32_16x16x32_bf16(xa[0][0], w0, z4, 0, 0, 0);
            dw0 = __builtin_amdgcn_mfma_f32_16x16x32_bf16(xa[0][1], w1, dw0, 0, 0, 0);
            f32x4 dw1 = __builtin_amdgcn_mfma_f32_16x16x32_bf16(xa[1][0], w0, z4, 0, 0, 0);
            dw1 = __builtin_amdgcn_mfma_f32_16x16x32_bf16(xa[1][1], w1, dw1, 0, 0, 0);
            int o = nt * 16 + l15;
            i32x2 q0 = {pack2(dw0[0], dw0[1]), pack2(dw0[2], dw0[3])};
            i32x2 q1 = {pack2(dw1[0], dw1[1]), pack2(dw1[2], dw1[3])};
            *(i32x2*)&FWT[o * 40 + quad * 4] = q0;
            *(i32x2*)&FWT[o * 40 + 16 + quad * 4] = q1;
        }

        // softmax * topo, in-place on Gh (25 active lanes), pad cols 25..31 zeroed
        if (lane < 25) {
            unsigned short* rowp = Gh + lane * 40;
            i32x4 ra = *(const i32x4*)rowp;
            i32x4 rb = *(const i32x4*)(rowp + 8);
            i32x4 rc = *(const i32x4*)(rowp + 16);
            float f[25];
            #pragma unroll
            for (int w = 0; w < 4; w++) {
                f[2 * w]      = __builtin_bit_cast(float, (unsigned)ra[w] << 16);
                f[2 * w + 1]  = __builtin_bit_cast(float, (unsigned)ra[w] & 0xFFFF0000u);
                f[8 + 2 * w]  = __builtin_bit_cast(float, (unsigned)rb[w] << 16);
                f[9 + 2 * w]  = __builtin_bit_cast(float, (unsigned)rb[w] & 0xFFFF0000u);
                f[16 + 2 * w] = __builtin_bit_cast(float, (unsigned)rc[w] << 16);
                f[17 + 2 * w] = __builtin_bit_cast(float, (unsigned)rc[w] & 0xFFFF0000u);
            }
            f[24] = bf2f(rowp[24]);
            float m = f[0];
            #pragma unroll
            for (int v = 1; v < 25; v++) m = fmaxf(m, f[v]);
            float s = 0.f;
            #pragma unroll
            for (int v = 0; v < 25; v++) { f[v] = __expf(f[v] - m); s += f[v]; }
            float inv = 1.0f / s;
            const float* tp = topo + h * 625 + lane * 25;
            #pragma unroll
            for (int v = 0; v < 25; v++) f[v] = f[v] * inv * tp[v];
            int d[16];
            #pragma unroll
            for (int p = 0; p < 12; p++) d[p] = pack2(f[2 * p], f[2 * p + 1]);
            d[12] = pack2(f[24], 0.f);
            d[13] = 0; d[14] = 0; d[15] = 0;
            *(i32x4*)rowp        = (i32x4){d[0], d[1], d[2], d[3]};
            *(i32x4*)(rowp + 8)  = (i32x4){d[4], d[5], d[6], d[7]};
            *(i32x4*)(rowp + 16) = (i32x4){d[8], d[9], d[10], d[11]};
            *(i32x4*)(rowp + 24) = (i32x4){d[12], d[13], d[14], d[15]};
        }

        // acc += G_h @ FW_h
        {
            bf16x8 ag0 = *(const bf16x8*)&Gh[l15 * 40 + quad * 8];
            bf16x8 ag1 = *(const bf16x8*)&Gh[(16 + l15) * 40 + quad * 8];
            #pragma unroll
            for (int nt = 0; nt < 4; nt++) {
                bf16x8 br = *(const bf16x8*)&FWT[(nt * 16 + l15) * 40 + quad * 8];
                acc[0][nt] = __builtin_amdgcn_mfma_f32_16x16x32_bf16(ag0, br, acc[0][nt], 0, 0, 0);
                acc[1][nt] = __builtin_amdgcn_mfma_f32_16x16x32_bf16(ag1, br, acc[1][nt], 0, 0, 0);
            }
        }
    }

    // ---- epilogue: BN + residual + ReLU, direct global store ----
    #pragma unroll
    for (int nt = 0; nt < 4; nt++) {
        int o = nt * 16 + l15;
        float gA = bnA[o], gB = bnB[o];
        #pragma unroll
        for (int mt = 0; mt < 2; mt++) {
            int ub = mt * 16 + quad * 4;
            #pragma unroll
            for (int r = 0; r < 4; r++) {
                int u = ub + r;
                if (u < 25) {
                    float val = acc[mt][nt][r] * gA + gB + xg[o * 6400 + u];
                    og[o * 6400 + u] = fmaxf(val, 0.f);
                }
            }
        }
    }
}

extern "C" void kernel_launch(void* const* d_in, const int* in_sizes, int n_in,
                              void* d_out, int out_size, void* d_ws, size_t ws_size,
                              hipStream_t stream) {
    const float* x      = (const float*)d_in[0];
    const float* ln_g   = (const float*)d_in[1];
    const float* ln_b   = (const float*)d_in[2];
    const float* w_qk   = (const float*)d_in[3];
    const float* b_qk   = (const float*)d_in[4];
    const float* topo   = (const float*)d_in[5];
    const float* conv_w = (const float*)d_in[6];
    const float* conv_b = (const float*)d_in[7];
    const float* bn_g   = (const float*)d_in[8];
    const float* bn_b   = (const float*)d_in[9];
    const float* bn_m   = (const float*)d_in[10];
    const float* bn_v   = (const float*)d_in[11];
    float* outp = (float*)d_out;
    unsigned short* wsp = (unsigned short*)d_ws;

    hipLaunchKernelGGL(prep_kernel, dim3(161), dim3(256), 0, stream,
                       w_qk, conv_w, conv_b, bn_g, bn_b, bn_m, bn_v, wsp);
    hipLaunchKernelGGL(sagc_kernel, dim3(2048), dim3(256), 0, stream,
                       x, ln_g, ln_b, b_qk, topo, (const unsigned short*)wsp, outp);
}